// Round 1
// baseline (186.648 us; speedup 1.0000x reference)
//
#include <hip/hip_runtime.h>

typedef _Float16 half8 __attribute__((ext_vector_type(8)));
typedef _Float16 half4 __attribute__((ext_vector_type(4)));
typedef float f32x4 __attribute__((ext_vector_type(4)));

#define NHEAD 12
#define HDIM  64
#define SEQ   1024
#define CDIM  768
#define O3    2304
#define MTOK  8192

__device__ __forceinline__ void load_lds16(const void* g, void* l) {
  __builtin_amdgcn_global_load_lds(
      (const __attribute__((address_space(1))) unsigned int*)g,
      (__attribute__((address_space(3))) unsigned int*)l, 16, 0, 0);
}

// ---------------- cast fp32 -> fp16 (4 elems/thread, vectorized) ----------------
__global__ __launch_bounds__(256) void cast_f2h(const float* __restrict__ in,
                                                _Float16* __restrict__ out) {
  size_t i = ((size_t)blockIdx.x * 256 + threadIdx.x) * 4;
  float4 v = *reinterpret_cast<const float4*>(in + i);
  half4 h;
  h[0] = (_Float16)v.x; h[1] = (_Float16)v.y; h[2] = (_Float16)v.z; h[3] = (_Float16)v.w;
  *reinterpret_cast<half4*>(out + i) = h;
}

// ---------------- QKV GEMM: x_h[8192,768] @ w_qkv_h[2304,768]^T ----------------
// Epilogue scatters to Q[B,H,N,D]*0.125 (fp16), K[B,H,N,D] (fp16), VT[B,H,D,N] (fp16).
__global__ __launch_bounds__(256) void qkv_gemm(const _Float16* __restrict__ A,
                                                const _Float16* __restrict__ Bw,
                                                _Float16* __restrict__ Qh,
                                                _Float16* __restrict__ Kh,
                                                _Float16* __restrict__ VT) {
  __shared__ _Float16 As[128 * 32];
  __shared__ _Float16 Bs[128 * 32];
  const int tid  = threadIdx.x;
  const int lane = tid & 63;
  const int wv   = tid >> 6;
  const int wm   = wv >> 1;
  const int wn   = wv & 1;
  const int fr   = lane & 15;
  const int kg   = lane >> 4;   // k-chunk id (8 halfs each)
  const int m0   = blockIdx.y * 128;
  const int n0   = blockIdx.x * 128;

  f32x4 acc[4][4];
#pragma unroll
  for (int i = 0; i < 4; ++i)
#pragma unroll
    for (int j = 0; j < 4; ++j) acc[i][j] = (f32x4){0.f, 0.f, 0.f, 0.f};

  for (int kt = 0; kt < CDIM; kt += 32) {
    // stage A tile (128x32 halfs): 512 16B-chunks, source XOR-preswizzled (chunk ^ row&3)
#pragma unroll
    for (int r = 0; r < 2; ++r) {
      const int c = r * 256 + tid;
      const int row = c >> 2, cc = c & 3;
      load_lds16(A + (size_t)(m0 + row) * CDIM + kt + ((cc ^ (row & 3)) * 8), &As[c * 8]);
    }
#pragma unroll
    for (int r = 0; r < 2; ++r) {
      const int c = r * 256 + tid;
      const int row = c >> 2, cc = c & 3;
      load_lds16(Bw + (size_t)(n0 + row) * CDIM + kt + ((cc ^ (row & 3)) * 8), &Bs[c * 8]);
    }
    __syncthreads();
    half8 a[4], b[4];
#pragma unroll
    for (int i = 0; i < 4; ++i) {
      const int row = wm * 64 + i * 16 + fr;
      a[i] = *reinterpret_cast<half8*>(&As[row * 32 + ((kg ^ (row & 3)) * 8)]);
    }
#pragma unroll
    for (int j = 0; j < 4; ++j) {
      const int row = wn * 64 + j * 16 + fr;
      b[j] = *reinterpret_cast<half8*>(&Bs[row * 32 + ((kg ^ (row & 3)) * 8)]);
    }
#pragma unroll
    for (int i = 0; i < 4; ++i)
#pragma unroll
      for (int j = 0; j < 4; ++j)
        acc[i][j] = __builtin_amdgcn_mfma_f32_16x16x32_f16(a[i], b[j], acc[i][j], 0, 0, 0);
    __syncthreads();
  }

  // epilogue: C/D layout col = lane&15, row = (lane>>4)*4 + reg  [m89-verified]
#pragma unroll
  for (int i = 0; i < 4; ++i) {
    const int mrow = m0 + wm * 64 + i * 16 + (lane >> 4) * 4;
#pragma unroll
    for (int j = 0; j < 4; ++j) {
      const int ocol = n0 + wn * 64 + j * 16 + fr;
      const int t  = ocol / CDIM;
      const int hd = ocol - t * CDIM;
      const int h  = hd >> 6, d = hd & 63;
#pragma unroll
      for (int r = 0; r < 4; ++r) {
        const int m  = mrow + r;
        const int bb = m >> 10, nn = m & 1023;
        const float v = acc[i][j][r];
        if (t == 0)
          Qh[(((size_t)bb * NHEAD + h) * SEQ + nn) * HDIM + d] = (_Float16)(v * 0.125f);
        else if (t == 1)
          Kh[(((size_t)bb * NHEAD + h) * SEQ + nn) * HDIM + d] = (_Float16)v;
        else
          VT[(((size_t)bb * NHEAD + h) * HDIM + d) * SEQ + nn] = (_Float16)v;
      }
    }
  }
}

// ---------------- flash attention: block = (bh, 128-row q-tile), 4 waves ----------------
__global__ __launch_bounds__(256) void attn_kernel(const _Float16* __restrict__ Qh,
                                                   const _Float16* __restrict__ Kh,
                                                   const _Float16* __restrict__ VT,
                                                   _Float16* __restrict__ AO) {
  __shared__ _Float16 Ks[64 * 64];        // [key][d], XOR-swizzled chunks
  __shared__ _Float16 Vs[64 * 64];        // [d][key-slice], XOR-swizzled chunks
  __shared__ _Float16 Ps[4 * 32 * 72];    // per-wave P, padded stride 72 halfs
  const int tid  = threadIdx.x;
  const int lane = tid & 63;
  const int w    = tid >> 6;
  const int fr   = lane & 15;
  const int kh   = (lane >> 4) * 8;       // k offset (halfs) within fragment
  const int bh   = blockIdx.x;            // 0..95
  const int qt   = blockIdx.y;            // 0..7
  const size_t qkbase = (size_t)bh * SEQ * HDIM;

  // Q fragments in registers (rows w*32 + fm*16 + fr, already pre-scaled by 0.125)
  half8 qa[2][2];
#pragma unroll
  for (int fm = 0; fm < 2; ++fm)
#pragma unroll
    for (int ks = 0; ks < 2; ++ks)
      qa[fm][ks] = *reinterpret_cast<const half8*>(
          &Qh[qkbase + (size_t)(qt * 128 + w * 32 + fm * 16 + fr) * HDIM + ks * 32 + kh]);

  f32x4 O[2][4];
  float mrun[2][4], lrun[2][4];
#pragma unroll
  for (int fm = 0; fm < 2; ++fm)
#pragma unroll
    for (int r = 0; r < 4; ++r) {
      mrun[fm][r] = -__builtin_inff();
      lrun[fm][r] = 0.f;
      if (r == 0) {}
    }
#pragma unroll
  for (int fm = 0; fm < 2; ++fm)
#pragma unroll
    for (int fd = 0; fd < 4; ++fd) O[fm][fd] = (f32x4){0.f, 0.f, 0.f, 0.f};

  for (int kt = 0; kt < SEQ; kt += 64) {
    __syncthreads();  // previous tile's PV reads done before overwrite
    // stage K tile [64 keys][64 d] and V^T tile [64 d][64 keys], swizzled source
#pragma unroll
    for (int r = 0; r < 2; ++r) {
      const int c = r * 256 + tid;
      const int row = c >> 3, cc = c & 7;
      load_lds16(&Kh[qkbase + (size_t)(kt + row) * HDIM + ((cc ^ (row & 7)) * 8)], &Ks[c * 8]);
    }
#pragma unroll
    for (int r = 0; r < 2; ++r) {
      const int c = r * 256 + tid;
      const int row = c >> 3, cc = c & 7;
      load_lds16(&VT[(size_t)bh * HDIM * SEQ + (size_t)row * SEQ + kt + ((cc ^ (row & 7)) * 8)],
                 &Vs[c * 8]);
    }
    __syncthreads();

    // S = Q K^T  (rows: wave's 32 q-rows; cols: 64 keys)
    f32x4 s[2][4];
#pragma unroll
    for (int fm = 0; fm < 2; ++fm)
#pragma unroll
      for (int fc = 0; fc < 4; ++fc) s[fm][fc] = (f32x4){0.f, 0.f, 0.f, 0.f};
#pragma unroll
    for (int fc = 0; fc < 4; ++fc) {
#pragma unroll
      for (int ks = 0; ks < 2; ++ks) {
        const int row = fc * 16 + fr;
        const int colh = ks * 32 + kh;
        half8 kb = *reinterpret_cast<half8*>(&Ks[row * 64 + (((colh >> 3) ^ (row & 7)) << 3)]);
#pragma unroll
        for (int fm = 0; fm < 2; ++fm)
          s[fm][fc] = __builtin_amdgcn_mfma_f32_16x16x32_f16(qa[fm][ks], kb, s[fm][fc], 0, 0, 0);
      }
    }

    // online softmax (row = fm*16 + (lane>>4)*4 + r; cols across fc and lane&15)
#pragma unroll
    for (int fm = 0; fm < 2; ++fm) {
#pragma unroll
      for (int r = 0; r < 4; ++r) {
        float mx = fmaxf(fmaxf(s[fm][0][r], s[fm][1][r]), fmaxf(s[fm][2][r], s[fm][3][r]));
        mx = fmaxf(mx, __shfl_xor(mx, 1));
        mx = fmaxf(mx, __shfl_xor(mx, 2));
        mx = fmaxf(mx, __shfl_xor(mx, 4));
        mx = fmaxf(mx, __shfl_xor(mx, 8));
        const float mnew = fmaxf(mrun[fm][r], mx);
        const float corr = __expf(mrun[fm][r] - mnew);
        mrun[fm][r] = mnew;
        float rs = 0.f;
#pragma unroll
        for (int fc = 0; fc < 4; ++fc) {
          const float p = __expf(s[fm][fc][r] - mnew);
          s[fm][fc][r] = p;
          rs += p;
        }
        rs += __shfl_xor(rs, 1);
        rs += __shfl_xor(rs, 2);
        rs += __shfl_xor(rs, 4);
        rs += __shfl_xor(rs, 8);
        lrun[fm][r] = lrun[fm][r] * corr + rs;
#pragma unroll
        for (int fd = 0; fd < 4; ++fd) O[fm][fd][r] *= corr;
      }
    }

    // write P (fp16) to this wave's padded LDS region
#pragma unroll
    for (int fm = 0; fm < 2; ++fm)
#pragma unroll
      for (int fc = 0; fc < 4; ++fc)
#pragma unroll
        for (int r = 0; r < 4; ++r)
          Ps[w * 2304 + (fm * 16 + (lane >> 4) * 4 + r) * 72 + fc * 16 + fr] =
              (_Float16)s[fm][fc][r];

    // PV: O += P[32x64] @ V[64x64]  (same-wave LDS dep; compiler inserts lgkmcnt)
#pragma unroll
    for (int ks = 0; ks < 2; ++ks) {
      half8 vb[4];
#pragma unroll
      for (int fd = 0; fd < 4; ++fd) {
        const int row = fd * 16 + fr;
        const int colh = ks * 32 + kh;
        vb[fd] = *reinterpret_cast<half8*>(&Vs[row * 64 + (((colh >> 3) ^ (row & 7)) << 3)]);
      }
#pragma unroll
      for (int fm = 0; fm < 2; ++fm) {
        half8 pa = *reinterpret_cast<half8*>(&Ps[w * 2304 + (fm * 16 + fr) * 72 + ks * 32 + kh]);
#pragma unroll
        for (int fd = 0; fd < 4; ++fd)
          O[fm][fd] = __builtin_amdgcn_mfma_f32_16x16x32_f16(pa, vb[fd], O[fm][fd], 0, 0, 0);
      }
    }
  }

  // epilogue: AO[b, n, h*64+d] fp16
  const int b = bh / NHEAD, h = bh % NHEAD;
#pragma unroll
  for (int fm = 0; fm < 2; ++fm) {
#pragma unroll
    for (int r = 0; r < 4; ++r) {
      const int n = qt * 128 + w * 32 + fm * 16 + (lane >> 4) * 4 + r;
      const float linv = 1.0f / lrun[fm][r];
#pragma unroll
      for (int fd = 0; fd < 4; ++fd)
        AO[((size_t)b * SEQ + n) * CDIM + h * HDIM + fd * 16 + fr] =
            (_Float16)(O[fm][fd][r] * linv);
    }
  }
}

// ---------------- proj GEMM: AO_h[8192,768] @ w_proj_h[768,768]^T + bias -> fp32 ----------------
__global__ __launch_bounds__(256) void proj_gemm(const _Float16* __restrict__ A,
                                                 const _Float16* __restrict__ Bw,
                                                 const float* __restrict__ bias,
                                                 float* __restrict__ Out) {
  __shared__ _Float16 As[128 * 32];
  __shared__ _Float16 Bs[128 * 32];
  const int tid  = threadIdx.x;
  const int lane = tid & 63;
  const int wv   = tid >> 6;
  const int wm   = wv >> 1;
  const int wn   = wv & 1;
  const int fr   = lane & 15;
  const int kg   = lane >> 4;
  const int m0   = blockIdx.y * 128;
  const int n0   = blockIdx.x * 128;

  f32x4 acc[4][4];
#pragma unroll
  for (int i = 0; i < 4; ++i)
#pragma unroll
    for (int j = 0; j < 4; ++j) acc[i][j] = (f32x4){0.f, 0.f, 0.f, 0.f};

  for (int kt = 0; kt < CDIM; kt += 32) {
#pragma unroll
    for (int r = 0; r < 2; ++r) {
      const int c = r * 256 + tid;
      const int row = c >> 2, cc = c & 3;
      load_lds16(A + (size_t)(m0 + row) * CDIM + kt + ((cc ^ (row & 3)) * 8), &As[c * 8]);
    }
#pragma unroll
    for (int r = 0; r < 2; ++r) {
      const int c = r * 256 + tid;
      const int row = c >> 2, cc = c & 3;
      load_lds16(Bw + (size_t)(n0 + row) * CDIM + kt + ((cc ^ (row & 3)) * 8), &Bs[c * 8]);
    }
    __syncthreads();
    half8 a[4], b[4];
#pragma unroll
    for (int i = 0; i < 4; ++i) {
      const int row = wm * 64 + i * 16 + fr;
      a[i] = *reinterpret_cast<half8*>(&As[row * 32 + ((kg ^ (row & 3)) * 8)]);
    }
#pragma unroll
    for (int j = 0; j < 4; ++j) {
      const int row = wn * 64 + j * 16 + fr;
      b[j] = *reinterpret_cast<half8*>(&Bs[row * 32 + ((kg ^ (row & 3)) * 8)]);
    }
#pragma unroll
    for (int i = 0; i < 4; ++i)
#pragma unroll
      for (int j = 0; j < 4; ++j)
        acc[i][j] = __builtin_amdgcn_mfma_f32_16x16x32_f16(a[i], b[j], acc[i][j], 0, 0, 0);
    __syncthreads();
  }

#pragma unroll
  for (int i = 0; i < 4; ++i) {
    const int mrow = m0 + wm * 64 + i * 16 + (lane >> 4) * 4;
#pragma unroll
    for (int j = 0; j < 4; ++j) {
      const int ocol = n0 + wn * 64 + j * 16 + fr;
      const float bv = bias[ocol];
#pragma unroll
      for (int r = 0; r < 4; ++r)
        Out[(size_t)(mrow + r) * CDIM + ocol] = acc[i][j][r] + bv;
    }
  }
}

extern "C" void kernel_launch(void* const* d_in, const int* in_sizes, int n_in,
                              void* d_out, int out_size, void* d_ws, size_t ws_size,
                              hipStream_t stream) {
  const float* x     = (const float*)d_in[0];   // [8,1024,768]
  const float* wqkv  = (const float*)d_in[1];   // [2304,768]
  const float* wproj = (const float*)d_in[2];   // [768,768]
  const float* bproj = (const float*)d_in[3];   // [768]
  float* out = (float*)d_out;

  char* ws = (char*)d_ws;
  // fp16 scratch layout (total ~67.6 MB)
  _Float16* x_h     = (_Float16*)(ws);
  _Float16* wqkv_h  = (_Float16*)(ws + 12582912);
  _Float16* wproj_h = (_Float16*)(ws + 16121856);
  _Float16* Qh      = (_Float16*)(ws + 17301504);
  _Float16* Kh      = (_Float16*)(ws + 29884416);
  _Float16* VT      = (_Float16*)(ws + 42467328);
  _Float16* AOh     = (_Float16*)(ws + 55050240);

  cast_f2h<<<6291456 / 1024, 256, 0, stream>>>(x, x_h);
  cast_f2h<<<1769472 / 1024, 256, 0, stream>>>(wqkv, wqkv_h);
  cast_f2h<<<589824 / 1024, 256, 0, stream>>>(wproj, wproj_h);

  qkv_gemm<<<dim3(O3 / 128, MTOK / 128), 256, 0, stream>>>(x_h, wqkv_h, Qh, Kh, VT);
  attn_kernel<<<dim3(96, 8), 256, 0, stream>>>(Qh, Kh, VT, AOh);
  proj_gemm<<<dim3(CDIM / 128, MTOK / 128), 256, 0, stream>>>(AOh, wproj_h, bproj, out);
}

// Round 3
// 160.773 us; speedup vs baseline: 1.1609x; 1.1609x over previous
//
#include <hip/hip_runtime.h>

typedef _Float16 half8 __attribute__((ext_vector_type(8)));
typedef _Float16 half4 __attribute__((ext_vector_type(4)));
typedef float f32x4 __attribute__((ext_vector_type(4)));

#define NHEAD 12
#define HDIM  64
#define SEQ   1024
#define CDIM  768
#define O3    2304
#define MTOK  8192

__device__ __forceinline__ void load_lds16(const void* g, void* l) {
  __builtin_amdgcn_global_load_lds(
      (const __attribute__((address_space(1))) unsigned int*)g,
      (__attribute__((address_space(3))) unsigned int*)l, 16, 0, 0);
}

// ---------------- cast fp32 -> fp16 (4 elems/thread, vectorized) ----------------
__global__ __launch_bounds__(256) void cast_f2h(const float* __restrict__ in,
                                                _Float16* __restrict__ out) {
  size_t i = ((size_t)blockIdx.x * 256 + threadIdx.x) * 4;
  float4 v = *reinterpret_cast<const float4*>(in + i);
  half4 h;
  h[0] = (_Float16)v.x; h[1] = (_Float16)v.y; h[2] = (_Float16)v.z; h[3] = (_Float16)v.w;
  *reinterpret_cast<half4*>(out + i) = h;
}

// ---------------- QKV GEMM: x_h[8192,768] @ w_qkv_h[2304,768]^T ----------------
__global__ __launch_bounds__(256) void qkv_gemm(const _Float16* __restrict__ A,
                                                const _Float16* __restrict__ Bw,
                                                _Float16* __restrict__ Qh,
                                                _Float16* __restrict__ Kh,
                                                _Float16* __restrict__ VT) {
  __shared__ _Float16 As[128 * 32];
  __shared__ _Float16 Bs[128 * 32];
  const int tid  = threadIdx.x;
  const int lane = tid & 63;
  const int wv   = tid >> 6;
  const int wm   = wv >> 1;
  const int wn   = wv & 1;
  const int fr   = lane & 15;
  const int kg   = lane >> 4;
  const int m0   = blockIdx.y * 128;
  const int n0   = blockIdx.x * 128;

  f32x4 acc[4][4];
#pragma unroll
  for (int i = 0; i < 4; ++i)
#pragma unroll
    for (int j = 0; j < 4; ++j) acc[i][j] = (f32x4){0.f, 0.f, 0.f, 0.f};

  for (int kt = 0; kt < CDIM; kt += 32) {
#pragma unroll
    for (int r = 0; r < 2; ++r) {
      const int c = r * 256 + tid;
      const int row = c >> 2, cc = c & 3;
      load_lds16(A + (size_t)(m0 + row) * CDIM + kt + ((cc ^ (row & 3)) * 8), &As[c * 8]);
    }
#pragma unroll
    for (int r = 0; r < 2; ++r) {
      const int c = r * 256 + tid;
      const int row = c >> 2, cc = c & 3;
      load_lds16(Bw + (size_t)(n0 + row) * CDIM + kt + ((cc ^ (row & 3)) * 8), &Bs[c * 8]);
    }
    __syncthreads();
    half8 a[4], b[4];
#pragma unroll
    for (int i = 0; i < 4; ++i) {
      const int row = wm * 64 + i * 16 + fr;
      a[i] = *reinterpret_cast<half8*>(&As[row * 32 + ((kg ^ (row & 3)) * 8)]);
    }
#pragma unroll
    for (int j = 0; j < 4; ++j) {
      const int row = wn * 64 + j * 16 + fr;
      b[j] = *reinterpret_cast<half8*>(&Bs[row * 32 + ((kg ^ (row & 3)) * 8)]);
    }
#pragma unroll
    for (int i = 0; i < 4; ++i)
#pragma unroll
      for (int j = 0; j < 4; ++j)
        acc[i][j] = __builtin_amdgcn_mfma_f32_16x16x32_f16(a[i], b[j], acc[i][j], 0, 0, 0);
    __syncthreads();
  }

#pragma unroll
  for (int i = 0; i < 4; ++i) {
    const int mrow = m0 + wm * 64 + i * 16 + (lane >> 4) * 4;
#pragma unroll
    for (int j = 0; j < 4; ++j) {
      const int ocol = n0 + wn * 64 + j * 16 + fr;
      const int t  = ocol / CDIM;
      const int hd = ocol - t * CDIM;
      const int h  = hd >> 6, d = hd & 63;
#pragma unroll
      for (int r = 0; r < 4; ++r) {
        const int m  = mrow + r;
        const int bb = m >> 10, nn = m & 1023;
        const float v = acc[i][j][r];
        if (t == 0)
          Qh[(((size_t)bb * NHEAD + h) * SEQ + nn) * HDIM + d] = (_Float16)(v * 0.125f);
        else if (t == 1)
          Kh[(((size_t)bb * NHEAD + h) * SEQ + nn) * HDIM + d] = (_Float16)v;
        else
          VT[(((size_t)bb * NHEAD + h) * HDIM + d) * SEQ + nn] = (_Float16)v;
      }
    }
  }
}

// ---------------- flash attention, swapped-QK^T in-register softmax ----------------
// block = (bh, 64-row q-tile), 4 waves x 16 q-rows. grid (96,16).
__global__ __launch_bounds__(256) void attn_kernel(const _Float16* __restrict__ Qh,
                                                   const _Float16* __restrict__ Kh,
                                                   const _Float16* __restrict__ VT,
                                                   _Float16* __restrict__ AO) {
  __shared__ _Float16 Ks[64 * 64];        // [key][d], XOR-swizzled 16B chunks
  __shared__ _Float16 Vs[64 * 64];        // [d][key], XOR-swizzled 16B chunks
  __shared__ _Float16 Ps[4 * 16 * 64];    // per-wave packed P [16 q][64 key], slot-swizzled
  const int tid  = threadIdx.x;
  const int lane = tid & 63;
  const int w    = tid >> 6;
  const int fr   = lane & 15;
  const int kg   = lane >> 4;
  const int kh   = kg * 8;
  const int bh   = blockIdx.x;            // 0..95
  const int qt   = blockIdx.y;            // 0..15
  const int q0   = qt * 64 + w * 16;      // wave's first q-row
  const size_t qkbase = (size_t)bh * SEQ * HDIM;
  char* const psw = (char*)&Ps[w * 16 * 64];

  // Q as B-operand fragments: lane (fr,kg) holds Q[q0+fr][ks*32+kg*8 .. +8] (pre-scaled)
  half8 qb[2];
#pragma unroll
  for (int ks = 0; ks < 2; ++ks)
    qb[ks] = *reinterpret_cast<const half8*>(
        &Qh[qkbase + (size_t)(q0 + fr) * HDIM + ks * 32 + kh]);

  f32x4 O[4];                 // O[fd][r]: row q_local = kg*4+r, col d = fd*16+fr
  float mrun = -__builtin_inff();   // stats for q-row fr (replicated over kg)
  float lrun = 0.f;
#pragma unroll
  for (int fd = 0; fd < 4; ++fd) O[fd] = (f32x4){0.f, 0.f, 0.f, 0.f};

  for (int kt = 0; kt < SEQ; kt += 64) {
    __syncthreads();
#pragma unroll
    for (int r = 0; r < 2; ++r) {
      const int c = r * 256 + tid;
      const int row = c >> 3, cc = c & 7;
      load_lds16(&Kh[qkbase + (size_t)(kt + row) * HDIM + ((cc ^ (row & 7)) * 8)], &Ks[c * 8]);
    }
#pragma unroll
    for (int r = 0; r < 2; ++r) {
      const int c = r * 256 + tid;
      const int row = c >> 3, cc = c & 7;
      load_lds16(&VT[(size_t)bh * HDIM * SEQ + (size_t)row * SEQ + kt + ((cc ^ (row & 7)) * 8)],
                 &Vs[c * 8]);
    }
    __syncthreads();

    // S^T = K Q^T : st[fc] holds S[key=fc*16+kg*4+r][q=fr]
    f32x4 st[4];
#pragma unroll
    for (int fc = 0; fc < 4; ++fc) st[fc] = (f32x4){0.f, 0.f, 0.f, 0.f};
#pragma unroll
    for (int ks = 0; ks < 2; ++ks) {
#pragma unroll
      for (int fc = 0; fc < 4; ++fc) {
        const int row = fc * 16 + fr;
        const int colh = ks * 32 + kh;
        half8 ka = *reinterpret_cast<half8*>(&Ks[row * 64 + (((colh >> 3) ^ (row & 7)) << 3)]);
        st[fc] = __builtin_amdgcn_mfma_f32_16x16x32_f16(ka, qb[ks], st[fc], 0, 0, 0);
      }
    }

    // online softmax for q-row fr: 16 in-register values + 2 shfl_xor combines
    float mx = st[0][0];
#pragma unroll
    for (int fc = 0; fc < 4; ++fc)
#pragma unroll
      for (int r = 0; r < 4; ++r) mx = fmaxf(mx, st[fc][r]);
    mx = fmaxf(mx, __shfl_xor(mx, 16));
    mx = fmaxf(mx, __shfl_xor(mx, 32));
    const float mnew = fmaxf(mrun, mx);
    const float corr = __expf(mrun - mnew);
    mrun = mnew;
    float rs = 0.f;
#pragma unroll
    for (int fc = 0; fc < 4; ++fc)
#pragma unroll
      for (int r = 0; r < 4; ++r) {
        const float p = __expf(st[fc][r] - mnew);
        st[fc][r] = p;
        rs += p;
      }
    rs += __shfl_xor(rs, 16);
    rs += __shfl_xor(rs, 32);
    lrun = lrun * corr + rs;

    // rescale O: need corr of rows q_local = kg*4+r (corr lives at lane fr==q_local)
#pragma unroll
    for (int r = 0; r < 4; ++r) {
      const float c4 = __shfl(corr, kg * 4 + r);
#pragma unroll
      for (int fd = 0; fd < 4; ++fd) O[fd][r] *= c4;
    }

    // pack P to fp16 (compiler emits v_cvt_pk) and store swizzled: 4x ds_write_b64
#pragma unroll
    for (int fc = 0; fc < 4; ++fc) {
      half4 pk;
      pk[0] = (_Float16)st[fc][0];
      pk[1] = (_Float16)st[fc][1];
      pk[2] = (_Float16)st[fc][2];
      pk[3] = (_Float16)st[fc][3];
      const int slot = (fc * 2 + (kg >> 1)) ^ (fr & 7);
      *reinterpret_cast<half4*>(psw + fr * 128 + slot * 16 + (kg & 1) * 8) = pk;
    }

    // PV: O += P[16x64] @ VT[64][64]^T  (same-wave LDS dep)
#pragma unroll
    for (int ks = 0; ks < 2; ++ks) {
      const int rslot = (ks * 4 + kg) ^ (fr & 7);
      half8 pa = *reinterpret_cast<half8*>(psw + fr * 128 + rslot * 16);
#pragma unroll
      for (int fd = 0; fd < 4; ++fd) {
        const int row = fd * 16 + fr;
        const int colh = ks * 32 + kh;
        half8 vb = *reinterpret_cast<half8*>(&Vs[row * 64 + (((colh >> 3) ^ (row & 7)) << 3)]);
        O[fd] = __builtin_amdgcn_mfma_f32_16x16x32_f16(pa, vb, O[fd], 0, 0, 0);
      }
    }
  }

  // epilogue: AO[b, n, h*64+d] fp16; l for row q lives at lane fr==q
  const int b = bh / NHEAD, h = bh % NHEAD;
  const float linv = 1.0f / lrun;
#pragma unroll
  for (int r = 0; r < 4; ++r) {
    const float lq = __shfl(linv, kg * 4 + r);
    const int n = q0 + kg * 4 + r;
#pragma unroll
    for (int fd = 0; fd < 4; ++fd)
      AO[((size_t)b * SEQ + n) * CDIM + h * HDIM + fd * 16 + fr] =
          (_Float16)(O[fd][r] * lq);
  }
}

// ---------------- proj GEMM: AO_h[8192,768] @ w_proj_h[768,768]^T + bias -> fp32 ----------------
__global__ __launch_bounds__(256) void proj_gemm(const _Float16* __restrict__ A,
                                                 const _Float16* __restrict__ Bw,
                                                 const float* __restrict__ bias,
                                                 float* __restrict__ Out) {
  __shared__ _Float16 As[128 * 32];
  __shared__ _Float16 Bs[128 * 32];
  const int tid  = threadIdx.x;
  const int lane = tid & 63;
  const int wv   = tid >> 6;
  const int wm   = wv >> 1;
  const int wn   = wv & 1;
  const int fr   = lane & 15;
  const int kg   = lane >> 4;
  const int m0   = blockIdx.y * 128;
  const int n0   = blockIdx.x * 128;

  f32x4 acc[4][4];
#pragma unroll
  for (int i = 0; i < 4; ++i)
#pragma unroll
    for (int j = 0; j < 4; ++j) acc[i][j] = (f32x4){0.f, 0.f, 0.f, 0.f};

  for (int kt = 0; kt < CDIM; kt += 32) {
#pragma unroll
    for (int r = 0; r < 2; ++r) {
      const int c = r * 256 + tid;
      const int row = c >> 2, cc = c & 3;
      load_lds16(A + (size_t)(m0 + row) * CDIM + kt + ((cc ^ (row & 3)) * 8), &As[c * 8]);
    }
#pragma unroll
    for (int r = 0; r < 2; ++r) {
      const int c = r * 256 + tid;
      const int row = c >> 2, cc = c & 3;
      load_lds16(Bw + (size_t)(n0 + row) * CDIM + kt + ((cc ^ (row & 3)) * 8), &Bs[c * 8]);
    }
    __syncthreads();
    half8 a[4], b[4];
#pragma unroll
    for (int i = 0; i < 4; ++i) {
      const int row = wm * 64 + i * 16 + fr;
      a[i] = *reinterpret_cast<half8*>(&As[row * 32 + ((kg ^ (row & 3)) * 8)]);
    }
#pragma unroll
    for (int j = 0; j < 4; ++j) {
      const int row = wn * 64 + j * 16 + fr;
      b[j] = *reinterpret_cast<half8*>(&Bs[row * 32 + ((kg ^ (row & 3)) * 8)]);
    }
#pragma unroll
    for (int i = 0; i < 4; ++i)
#pragma unroll
      for (int j = 0; j < 4; ++j)
        acc[i][j] = __builtin_amdgcn_mfma_f32_16x16x32_f16(a[i], b[j], acc[i][j], 0, 0, 0);
    __syncthreads();
  }

#pragma unroll
  for (int i = 0; i < 4; ++i) {
    const int mrow = m0 + wm * 64 + i * 16 + (lane >> 4) * 4;
#pragma unroll
    for (int j = 0; j < 4; ++j) {
      const int ocol = n0 + wn * 64 + j * 16 + fr;
      const float bv = bias[ocol];
#pragma unroll
      for (int r = 0; r < 4; ++r)
        Out[(size_t)(mrow + r) * CDIM + ocol] = acc[i][j][r] + bv;
    }
  }
}

extern "C" void kernel_launch(void* const* d_in, const int* in_sizes, int n_in,
                              void* d_out, int out_size, void* d_ws, size_t ws_size,
                              hipStream_t stream) {
  const float* x     = (const float*)d_in[0];
  const float* wqkv  = (const float*)d_in[1];
  const float* wproj = (const float*)d_in[2];
  const float* bproj = (const float*)d_in[3];
  float* out = (float*)d_out;

  char* ws = (char*)d_ws;
  _Float16* x_h     = (_Float16*)(ws);
  _Float16* wqkv_h  = (_Float16*)(ws + 12582912);
  _Float16* wproj_h = (_Float16*)(ws + 16121856);
  _Float16* Qh      = (_Float16*)(ws + 17301504);
  _Float16* Kh      = (_Float16*)(ws + 29884416);
  _Float16* VT      = (_Float16*)(ws + 42467328);
  _Float16* AOh     = (_Float16*)(ws + 55050240);

  cast_f2h<<<6291456 / 1024, 256, 0, stream>>>(x, x_h);
  cast_f2h<<<1769472 / 1024, 256, 0, stream>>>(wqkv, wqkv_h);
  cast_f2h<<<589824 / 1024, 256, 0, stream>>>(wproj, wproj_h);

  qkv_gemm<<<dim3(O3 / 128, MTOK / 128), 256, 0, stream>>>(x_h, wqkv_h, Qh, Kh, VT);
  attn_kernel<<<dim3(96, 16), 256, 0, stream>>>(Qh, Kh, VT, AOh);
  proj_gemm<<<dim3(CDIM / 128, MTOK / 128), 256, 0, stream>>>(AOh, wproj_h, bproj, out);
}